// Round 2
// baseline (1292.704 us; speedup 1.0000x reference)
//
#include <hip/hip_runtime.h>
#include <hip/hip_bf16.h>

// Problem constants (fixed by reference)
#define B_   2
#define S_   2048
#define HID_ 1024
#define NH_  16
#define HD_  64
// GRID_SIZE=16 -> 256 tokens/frame; ROT_DIM=20 per axial segment, 3 segments, 4-dim tail

// ---------------------------------------------------------------------------
// Kernel 1: QKV projection + bias + axial RoPE epilogue (Q,K only).
// X[4096][1024] fp32 @ W[1024][1024] fp32 -> fp32 [b][h][s][64] in workspace.
// grid (16 n-tiles, 64 m-tiles, z=0/1/2 for Q/K/V), block 256, 64x64 tile, BK=16.
// ---------------------------------------------------------------------------
__global__ __launch_bounds__(256) void proj_qkv_kernel(
    const float* __restrict__ X,
    const float* __restrict__ Wq, const float* __restrict__ bq,
    const float* __restrict__ Wk, const float* __restrict__ bk,
    const float* __restrict__ Wv, const float* __restrict__ bv,
    float* __restrict__ Qw, float* __restrict__ Kw, float* __restrict__ Vw)
{
    const int z = blockIdx.z;
    const float* __restrict__ W    = (z == 0) ? Wq : (z == 1) ? Wk : Wv;
    const float* __restrict__ bias = (z == 0) ? bq : (z == 1) ? bk : bv;

    const int n0 = blockIdx.x * 64;
    const int m0 = blockIdx.y * 64;
    const int t  = threadIdx.x;
    const int tx = t & 15, ty = t >> 4;

    __shared__ float As[64][17];   // +1 pad: conflict-free row reads
    __shared__ float Bs[16][64];   // kk uniform at read time -> no conflicts

    float acc[4][4] = {};

    const int ar = t >> 2, ac = (t & 3) * 4;   // A staging: 64 rows x 16 k
    const int br = ty,     bc = tx * 4;        // B staging: 16 k x 64 n

    for (int k0 = 0; k0 < HID_; k0 += 16) {
        {
            const float4 f = *reinterpret_cast<const float4*>(
                (const void*)(X + (size_t)(m0 + ar) * HID_ + k0 + ac));
            As[ar][ac + 0] = f.x; As[ar][ac + 1] = f.y;
            As[ar][ac + 2] = f.z; As[ar][ac + 3] = f.w;
        }
        {
            const float4 f = *reinterpret_cast<const float4*>(
                (const void*)(W + (size_t)(k0 + br) * HID_ + n0 + bc));
            Bs[br][bc + 0] = f.x; Bs[br][bc + 1] = f.y;
            Bs[br][bc + 2] = f.z; Bs[br][bc + 3] = f.w;
        }
        __syncthreads();
        #pragma unroll
        for (int kk = 0; kk < 16; ++kk) {
            float a0 = As[ty * 4 + 0][kk], a1 = As[ty * 4 + 1][kk];
            float a2 = As[ty * 4 + 2][kk], a3 = As[ty * 4 + 3][kk];
            float b0 = Bs[kk][tx * 4 + 0], b1 = Bs[kk][tx * 4 + 1];
            float b2 = Bs[kk][tx * 4 + 2], b3 = Bs[kk][tx * 4 + 3];
            acc[0][0] += a0 * b0; acc[0][1] += a0 * b1; acc[0][2] += a0 * b2; acc[0][3] += a0 * b3;
            acc[1][0] += a1 * b0; acc[1][1] += a1 * b1; acc[1][2] += a1 * b2; acc[1][3] += a1 * b3;
            acc[2][0] += a2 * b0; acc[2][1] += a2 * b1; acc[2][2] += a2 * b2; acc[2][3] += a2 * b3;
            acc[3][0] += a3 * b0; acc[3][1] += a3 * b1; acc[3][2] += a3 * b2; acc[3][3] += a3 * b3;
        }
        __syncthreads();
    }

    // bias for this thread's 4 columns
    float bcol[4];
    {
        const float4 f = *reinterpret_cast<const float4*>(
            (const void*)(bias + n0 + tx * 4));
        bcol[0] = f.x; bcol[1] = f.y; bcol[2] = f.z; bcol[3] = f.w;
    }

    const int h  = n0 >> 6;        // whole 64-col tile lives in one head
    const int d0 = tx * 4;         // head-dim base (n0 % 64 == 0)
    float* __restrict__ dst = (z == 0) ? Qw : (z == 1) ? Kw : Vw;

    #pragma unroll
    for (int i = 0; i < 4; ++i) {
        const int m = m0 + ty * 4 + i;
        const int b = m >> 11;         // / 2048
        const int s = m & 2047;
        float vals[4];
        #pragma unroll
        for (int j = 0; j < 4; ++j) vals[j] = acc[i][j] + bcol[j];

        if (z < 2) {
            // axial RoPE: seg 0 -> frame id, 1 -> height, 2 -> width; tail d>=60 untouched
            const int frame = s >> 8;          // /256
            const int rem   = s & 255;
            const int hrow  = rem >> 4;
            const int wcol  = rem & 15;
            #pragma unroll
            for (int jp = 0; jp < 4; jp += 2) {
                const int d = d0 + jp;         // even, pair (d, d+1) both in this thread
                if (d < 60) {
                    const int seg = d / 20;
                    const int dd  = d - seg * 20;      // even local index in [0,20)
                    const float pos = (float)(seg == 0 ? frame : (seg == 1 ? hrow : wcol));
                    // tiled sin/cos: index = local_d % 10 (even/odd of a pair DIFFER)
                    const int i0 = dd % 10;
                    const int i1 = (dd + 1) % 10;
                    // omega = 10000^(-idx/10) = exp(-ln(10000)/10 * idx)
                    const float a0 = pos * __expf(-0.9210340372f * (float)i0);
                    const float a1 = pos * __expf(-0.9210340372f * (float)i1);
                    float s0, c0, s1, c1;
                    sincosf(a0, &s0, &c0);
                    sincosf(a1, &s1, &c1);
                    const float x0 = vals[jp], x1 = vals[jp + 1];
                    vals[jp]     = x0 * c0 - x1 * s0;
                    vals[jp + 1] = x1 * c1 + x0 * s1;
                }
            }
        }

        const size_t base = ((size_t)((b * NH_ + h) * S_ + s)) * HD_ + d0;
        #pragma unroll
        for (int j = 0; j < 4; ++j) dst[base + j] = vals[j];
    }
}

// ---------------------------------------------------------------------------
// Kernel 2: flash attention. One block per (b,h, 64-row q tile).
// Q,K,V fp32 [bh][2048][64]; ctx -> fp32 [b][s][h*64+d].
// ---------------------------------------------------------------------------
__global__ __launch_bounds__(256) void attn_kernel(
    const float* __restrict__ Q, const float* __restrict__ K,
    const float* __restrict__ V, float* __restrict__ CTX)
{
    const int q0 = blockIdx.x * 64;
    const int bh = blockIdx.y;
    const int b  = bh >> 4, h = bh & 15;
    const int t  = threadIdx.x;
    const int tx = t & 15, ty = t >> 4;

    __shared__ float Qs[64 * 65];
    __shared__ float Ks[64 * 65];   // reused for P after the score phase
    __shared__ float Vs[64 * 65];

    const float* __restrict__ Qg = Q + (size_t)bh * S_ * HD_;
    const float* __restrict__ Kg = K + (size_t)bh * S_ * HD_;
    const float* __restrict__ Vg = V + (size_t)bh * S_ * HD_;

    // stage Q tile once, pre-scaled by 1/sqrt(64)
    for (int e = t; e < 4096; e += 256) {
        const int r = e >> 6, c = e & 63;
        Qs[r * 65 + c] = Qg[(size_t)(q0 + r) * HD_ + c] * 0.125f;
    }

    float m_[4], l_[4], o_[4][4];
    #pragma unroll
    for (int i = 0; i < 4; ++i) {
        m_[i] = -1e30f; l_[i] = 0.f;
        #pragma unroll
        for (int j = 0; j < 4; ++j) o_[i][j] = 0.f;
    }

    for (int k0 = 0; k0 < S_; k0 += 64) {
        __syncthreads();   // prior-iter readers of Ks(P)/Vs done; also covers Qs staging
        for (int e = t; e < 4096; e += 256) {
            const int r = e >> 6, c = e & 63;
            Ks[r * 65 + c] = Kg[(size_t)(k0 + r) * HD_ + c];
            Vs[r * 65 + c] = Vg[(size_t)(k0 + r) * HD_ + c];
        }
        __syncthreads();

        // scores: acc[i][j] = (Q*0.125)[q0+ty*4+i] . K[k0+tx*4+j]
        float acc[4][4] = {};
        for (int d = 0; d < 64; ++d) {
            float a0 = Qs[(ty * 4 + 0) * 65 + d], a1 = Qs[(ty * 4 + 1) * 65 + d];
            float a2 = Qs[(ty * 4 + 2) * 65 + d], a3 = Qs[(ty * 4 + 3) * 65 + d];
            float b0 = Ks[(tx * 4 + 0) * 65 + d], b1 = Ks[(tx * 4 + 1) * 65 + d];
            float b2 = Ks[(tx * 4 + 2) * 65 + d], b3 = Ks[(tx * 4 + 3) * 65 + d];
            acc[0][0] += a0 * b0; acc[0][1] += a0 * b1; acc[0][2] += a0 * b2; acc[0][3] += a0 * b3;
            acc[1][0] += a1 * b0; acc[1][1] += a1 * b1; acc[1][2] += a1 * b2; acc[1][3] += a1 * b3;
            acc[2][0] += a2 * b0; acc[2][1] += a2 * b1; acc[2][2] += a2 * b2; acc[2][3] += a2 * b3;
            acc[3][0] += a3 * b0; acc[3][1] += a3 * b1; acc[3][2] += a3 * b2; acc[3][3] += a3 * b3;
        }

        // online softmax per q-row; row = 16 lanes sharing ty (shfl_xor 8,4,2,1)
        float p[4][4];
        #pragma unroll
        for (int i = 0; i < 4; ++i) {
            float tmax = fmaxf(fmaxf(acc[i][0], acc[i][1]), fmaxf(acc[i][2], acc[i][3]));
            #pragma unroll
            for (int off = 8; off >= 1; off >>= 1) tmax = fmaxf(tmax, __shfl_xor(tmax, off));
            const float mnew  = fmaxf(m_[i], tmax);
            const float alpha = __expf(m_[i] - mnew);
            float psum = 0.f;
            #pragma unroll
            for (int j = 0; j < 4; ++j) { p[i][j] = __expf(acc[i][j] - mnew); psum += p[i][j]; }
            #pragma unroll
            for (int off = 8; off >= 1; off >>= 1) psum += __shfl_xor(psum, off);
            l_[i] = l_[i] * alpha + psum;
            m_[i] = mnew;
            #pragma unroll
            for (int j = 0; j < 4; ++j) o_[i][j] *= alpha;
        }

        __syncthreads();           // all score-phase reads of Ks complete
        #pragma unroll
        for (int i = 0; i < 4; ++i)
            #pragma unroll
            for (int j = 0; j < 4; ++j)
                Ks[(ty * 4 + i) * 65 + tx * 4 + j] = p[i][j];   // P into Ks buffer
        __syncthreads();

        // O += P @ V   (o_[i][j]: row q0+ty*4+i, dim tx*4+j)
        for (int kj = 0; kj < 64; ++kj) {
            float p0 = Ks[(ty * 4 + 0) * 65 + kj], p1 = Ks[(ty * 4 + 1) * 65 + kj];
            float p2 = Ks[(ty * 4 + 2) * 65 + kj], p3 = Ks[(ty * 4 + 3) * 65 + kj];
            float v0 = Vs[kj * 65 + tx * 4 + 0], v1 = Vs[kj * 65 + tx * 4 + 1];
            float v2 = Vs[kj * 65 + tx * 4 + 2], v3 = Vs[kj * 65 + tx * 4 + 3];
            o_[0][0] += p0 * v0; o_[0][1] += p0 * v1; o_[0][2] += p0 * v2; o_[0][3] += p0 * v3;
            o_[1][0] += p1 * v0; o_[1][1] += p1 * v1; o_[1][2] += p1 * v2; o_[1][3] += p1 * v3;
            o_[2][0] += p2 * v0; o_[2][1] += p2 * v1; o_[2][2] += p2 * v2; o_[2][3] += p2 * v3;
            o_[3][0] += p3 * v0; o_[3][1] += p3 * v1; o_[3][2] += p3 * v2; o_[3][3] += p3 * v3;
        }
    }

    #pragma unroll
    for (int i = 0; i < 4; ++i) {
        const int s = q0 + ty * 4 + i;
        const float inv = 1.0f / l_[i];
        const size_t base = ((size_t)(b * S_ + s)) * HID_ + h * HD_ + tx * 4;
        #pragma unroll
        for (int j = 0; j < 4; ++j) CTX[base + j] = o_[i][j] * inv;
    }
}

// ---------------------------------------------------------------------------
// Kernel 3: output projection. CTX fp32 [4096][1024] @ Wo fp32 + bo -> fp32 out.
// ---------------------------------------------------------------------------
__global__ __launch_bounds__(256) void out_proj_kernel(
    const float* __restrict__ CTX, const float* __restrict__ Wo,
    const float* __restrict__ bo, float* __restrict__ out)
{
    const int n0 = blockIdx.x * 64;
    const int m0 = blockIdx.y * 64;
    const int t  = threadIdx.x;
    const int tx = t & 15, ty = t >> 4;

    __shared__ float As[64][17];
    __shared__ float Bs[16][64];

    float acc[4][4] = {};

    const int ar = t >> 2, ac = (t & 3) * 4;
    const int br = ty,     bc = tx * 4;

    for (int k0 = 0; k0 < HID_; k0 += 16) {
        {
            const float4 f = *reinterpret_cast<const float4*>(
                (const void*)(CTX + (size_t)(m0 + ar) * HID_ + k0 + ac));
            As[ar][ac + 0] = f.x; As[ar][ac + 1] = f.y;
            As[ar][ac + 2] = f.z; As[ar][ac + 3] = f.w;
        }
        {
            const float4 f = *reinterpret_cast<const float4*>(
                (const void*)(Wo + (size_t)(k0 + br) * HID_ + n0 + bc));
            Bs[br][bc + 0] = f.x; Bs[br][bc + 1] = f.y;
            Bs[br][bc + 2] = f.z; Bs[br][bc + 3] = f.w;
        }
        __syncthreads();
        #pragma unroll
        for (int kk = 0; kk < 16; ++kk) {
            float a0 = As[ty * 4 + 0][kk], a1 = As[ty * 4 + 1][kk];
            float a2 = As[ty * 4 + 2][kk], a3 = As[ty * 4 + 3][kk];
            float b0 = Bs[kk][tx * 4 + 0], b1 = Bs[kk][tx * 4 + 1];
            float b2 = Bs[kk][tx * 4 + 2], b3 = Bs[kk][tx * 4 + 3];
            acc[0][0] += a0 * b0; acc[0][1] += a0 * b1; acc[0][2] += a0 * b2; acc[0][3] += a0 * b3;
            acc[1][0] += a1 * b0; acc[1][1] += a1 * b1; acc[1][2] += a1 * b2; acc[1][3] += a1 * b3;
            acc[2][0] += a2 * b0; acc[2][1] += a2 * b1; acc[2][2] += a2 * b2; acc[2][3] += a2 * b3;
            acc[3][0] += a3 * b0; acc[3][1] += a3 * b1; acc[3][2] += a3 * b2; acc[3][3] += a3 * b3;
        }
        __syncthreads();
    }

    float bcol[4];
    {
        const float4 f = *reinterpret_cast<const float4*>(
            (const void*)(bo + n0 + tx * 4));
        bcol[0] = f.x; bcol[1] = f.y; bcol[2] = f.z; bcol[3] = f.w;
    }

    #pragma unroll
    for (int i = 0; i < 4; ++i) {
        const int m = m0 + ty * 4 + i;
        const size_t base = (size_t)m * HID_ + n0 + tx * 4;
        #pragma unroll
        for (int j = 0; j < 4; ++j)
            out[base + j] = acc[i][j] + bcol[j];
    }
}

// ---------------------------------------------------------------------------
extern "C" void kernel_launch(void* const* d_in, const int* in_sizes, int n_in,
                              void* d_out, int out_size, void* d_ws, size_t ws_size,
                              hipStream_t stream)
{
    const float* X  = (const float*)d_in[0];
    const float* Wq = (const float*)d_in[1];
    const float* bq = (const float*)d_in[2];
    const float* Wk = (const float*)d_in[3];
    const float* bk = (const float*)d_in[4];
    const float* Wv = (const float*)d_in[5];
    const float* bv = (const float*)d_in[6];
    const float* Wo = (const float*)d_in[7];
    const float* bo = (const float*)d_in[8];
    float* out = (float*)d_out;

    // workspace: Q,K,V fp32 [2*16*2048*64] each, CTX fp32 [2*2048*1024] = 64 MB total
    const size_t QKV = (size_t)B_ * NH_ * S_ * HD_;   // 4,194,304
    float* Qw = (float*)d_ws;
    float* Kw = Qw + QKV;
    float* Vw = Kw + QKV;
    float* Cw = Vw + QKV;

    proj_qkv_kernel<<<dim3(16, 64, 3), 256, 0, stream>>>(X, Wq, bq, Wk, bk, Wv, bv, Qw, Kw, Vw);
    attn_kernel<<<dim3(S_ / 64, B_ * NH_), 256, 0, stream>>>(Qw, Kw, Vw, Cw);
    out_proj_kernel<<<dim3(16, 64), 256, 0, stream>>>(Cw, Wo, bo, out);
}

// Round 3
// 703.140 us; speedup vs baseline: 1.8385x; 1.8385x over previous
//
#include <hip/hip_runtime.h>
#include <hip/hip_bf16.h>

// Problem constants (fixed by reference)
#define B_   2
#define S_   2048
#define HID_ 1024
#define NH_  16
#define HD_  64
#define LP   72   // padded LDS row stride in bf16 elems (144 B = 9*16B -> 16B aligned, odd dword stride)

typedef __hip_bfloat16 bf16;
typedef __attribute__((ext_vector_type(8))) short s8v;   // 8 bf16 = 4 VGPR (MFMA A/B frag)
typedef __attribute__((ext_vector_type(4))) float f4v;   // MFMA C/D frag

__device__ __forceinline__ unsigned short f2b_rne(float x) {
    unsigned int u = __float_as_uint(x);
    u += 0x7fffu + ((u >> 16) & 1u);
    return (unsigned short)(u >> 16);
}

// ---------------------------------------------------------------------------
// Kernel 1: QKV projection + bias + axial RoPE epilogue (Q,K only).
// X[4096][1024] fp32 @ W[1024][1024] fp32 -> bf16 Q,K [bh][s][64], V^T [bh][d][s].
// ---------------------------------------------------------------------------
__global__ __launch_bounds__(256) void proj_qkv_kernel(
    const float* __restrict__ X,
    const float* __restrict__ Wq, const float* __restrict__ bq,
    const float* __restrict__ Wk, const float* __restrict__ bk,
    const float* __restrict__ Wv, const float* __restrict__ bv,
    bf16* __restrict__ Qb, bf16* __restrict__ Kb, bf16* __restrict__ Vt)
{
    const int z = blockIdx.z;
    const float* __restrict__ W    = (z == 0) ? Wq : (z == 1) ? Wk : Wv;
    const float* __restrict__ bias = (z == 0) ? bq : (z == 1) ? bk : bv;

    const int n0 = blockIdx.x * 64;
    const int m0 = blockIdx.y * 64;
    const int t  = threadIdx.x;
    const int tx = t & 15, ty = t >> 4;

    __shared__ float As[64][17];
    __shared__ float Bs[16][64];

    float acc[4][4] = {};

    const int ar = t >> 2, ac = (t & 3) * 4;
    const int br = ty,     bc = tx * 4;

    for (int k0 = 0; k0 < HID_; k0 += 16) {
        {
            const float4 f = *reinterpret_cast<const float4*>(
                (const void*)(X + (size_t)(m0 + ar) * HID_ + k0 + ac));
            As[ar][ac + 0] = f.x; As[ar][ac + 1] = f.y;
            As[ar][ac + 2] = f.z; As[ar][ac + 3] = f.w;
        }
        {
            const float4 f = *reinterpret_cast<const float4*>(
                (const void*)(W + (size_t)(k0 + br) * HID_ + n0 + bc));
            Bs[br][bc + 0] = f.x; Bs[br][bc + 1] = f.y;
            Bs[br][bc + 2] = f.z; Bs[br][bc + 3] = f.w;
        }
        __syncthreads();
        #pragma unroll
        for (int kk = 0; kk < 16; ++kk) {
            float a0 = As[ty * 4 + 0][kk], a1 = As[ty * 4 + 1][kk];
            float a2 = As[ty * 4 + 2][kk], a3 = As[ty * 4 + 3][kk];
            float b0 = Bs[kk][tx * 4 + 0], b1 = Bs[kk][tx * 4 + 1];
            float b2 = Bs[kk][tx * 4 + 2], b3 = Bs[kk][tx * 4 + 3];
            acc[0][0] += a0 * b0; acc[0][1] += a0 * b1; acc[0][2] += a0 * b2; acc[0][3] += a0 * b3;
            acc[1][0] += a1 * b0; acc[1][1] += a1 * b1; acc[1][2] += a1 * b2; acc[1][3] += a1 * b3;
            acc[2][0] += a2 * b0; acc[2][1] += a2 * b1; acc[2][2] += a2 * b2; acc[2][3] += a2 * b3;
            acc[3][0] += a3 * b0; acc[3][1] += a3 * b1; acc[3][2] += a3 * b2; acc[3][3] += a3 * b3;
        }
        __syncthreads();
    }

    float bcol[4];
    {
        const float4 f = *reinterpret_cast<const float4*>(
            (const void*)(bias + n0 + tx * 4));
        bcol[0] = f.x; bcol[1] = f.y; bcol[2] = f.z; bcol[3] = f.w;
    }

    const int h  = n0 >> 6;
    const int d0 = tx * 4;

    #pragma unroll
    for (int i = 0; i < 4; ++i) {
        const int m = m0 + ty * 4 + i;
        const int b = m >> 11;
        const int s = m & 2047;
        float vals[4];
        #pragma unroll
        for (int j = 0; j < 4; ++j) vals[j] = acc[i][j] + bcol[j];

        if (z < 2) {
            // axial RoPE: seg 0 -> frame, 1 -> height, 2 -> width; tail d>=60 untouched
            const int frame = s >> 8;
            const int rem   = s & 255;
            const int hrow  = rem >> 4;
            const int wcol  = rem & 15;
            #pragma unroll
            for (int jp = 0; jp < 4; jp += 2) {
                const int d = d0 + jp;
                if (d < 60) {
                    const int seg = d / 20;
                    const int dd  = d - seg * 20;
                    const float pos = (float)(seg == 0 ? frame : (seg == 1 ? hrow : wcol));
                    const int i0 = dd % 10;
                    const int i1 = (dd + 1) % 10;
                    const float a0 = pos * __expf(-0.9210340372f * (float)i0);
                    const float a1 = pos * __expf(-0.9210340372f * (float)i1);
                    float s0, c0, s1, c1;
                    sincosf(a0, &s0, &c0);
                    sincosf(a1, &s1, &c1);
                    const float x0 = vals[jp], x1 = vals[jp + 1];
                    vals[jp]     = x0 * c0 - x1 * s0;
                    vals[jp + 1] = x1 * c1 + x0 * s1;
                }
            }
            bf16* __restrict__ p = (z == 0 ? Qb : Kb)
                + ((size_t)((b * NH_ + h) * S_ + s)) * HD_ + d0;
            #pragma unroll
            for (int j = 0; j < 4; ++j) p[j] = __float2bfloat16(vals[j]);
        } else {
            // V stored TRANSPOSED: [bh][d][s]
            #pragma unroll
            for (int j = 0; j < 4; ++j)
                Vt[((size_t)(b * NH_ + h) * HD_ + d0 + j) * S_ + s] = __float2bfloat16(vals[j]);
        }
    }
}

// ---------------------------------------------------------------------------
// Kernel 2: MFMA flash attention. Block = 4 waves = one (bh, 64-row q tile).
// Q,K bf16 [bh][s][64]; V^T bf16 [bh][d][s]; ctx -> fp32 [b][s][hid].
// Wave w owns q rows [w*16, w*16+16). Per 64-k-tile:
//   scores: 4 n-tiles x 2 chunks of mfma_f32_16x16x32_bf16 (Q as A, K as B)
//   online softmax on C-layout regs (row=quad*4+r, col=ntile*16+lane15)
//   P -> LDS (C-layout write, A-layout read; per-wave 16-row slice)
//   PV: 4 d-tiles x 2 chunks (P as A, V^T as B)
// ---------------------------------------------------------------------------
__global__ __launch_bounds__(256) void attn_kernel(
    const bf16* __restrict__ Qb, const bf16* __restrict__ Kb,
    const bf16* __restrict__ Vt, float* __restrict__ CTX)
{
    const int q0 = blockIdx.x * 64;
    const int bh = blockIdx.y;
    const int b  = bh >> 4, h = bh & 15;
    const int t  = threadIdx.x;
    const int wv = t >> 6;
    const int ln = t & 63;
    const int l15 = ln & 15, qd = ln >> 4;

    __shared__ unsigned short Ks[64 * LP];   // [k_local][d]
    __shared__ unsigned short Vs[64 * LP];   // [d][k_local]   (V^T tile)
    __shared__ unsigned short Ps[64 * LP];   // [q_local][k_local], wave w uses rows w*16..+15

    // Q A-fragments once, straight from global: A[m=l15][k=qd*8+j]
    const bf16* Qrow = Qb + ((size_t)bh * S_ + q0 + wv * 16 + l15) * HD_ + qd * 8;
    const s8v aq0 = *reinterpret_cast<const s8v*>(Qrow);
    const s8v aq1 = *reinterpret_cast<const s8v*>(Qrow + 32);

    f4v oacc[4];
    float m_[4], l_[4];
    #pragma unroll
    for (int r = 0; r < 4; ++r) {
        m_[r] = -1e30f; l_[r] = 0.f;
        oacc[r] = (f4v){0.f, 0.f, 0.f, 0.f};
    }

    const bf16* __restrict__ Kg = Kb + (size_t)bh * S_ * HD_;
    const bf16* __restrict__ Vg = Vt + (size_t)bh * HD_ * S_;

    const int sr = t >> 3;           // staging row 0..31 (and +32)
    const int sc = (t & 7) * 8;      // staging col chunk

    for (int k0 = 0; k0 < S_; k0 += 64) {
        __syncthreads();   // prior-iteration frag reads of Ks/Vs complete
        *reinterpret_cast<s8v*>(&Ks[sr * LP + sc]) =
            *reinterpret_cast<const s8v*>(Kg + (size_t)(k0 + sr) * HD_ + sc);
        *reinterpret_cast<s8v*>(&Ks[(sr + 32) * LP + sc]) =
            *reinterpret_cast<const s8v*>(Kg + (size_t)(k0 + sr + 32) * HD_ + sc);
        *reinterpret_cast<s8v*>(&Vs[sr * LP + sc]) =
            *reinterpret_cast<const s8v*>(Vg + (size_t)sr * S_ + k0 + sc);
        *reinterpret_cast<s8v*>(&Vs[(sr + 32) * LP + sc]) =
            *reinterpret_cast<const s8v*>(Vg + (size_t)(sr + 32) * S_ + k0 + sc);
        __syncthreads();

        // ---- scores: S[m][n] = sum_k Q[m][k] K[n][k]  (B[n=l15][k=qd*8+j] = K row reads)
        f4v sc4[4];
        #pragma unroll
        for (int nt = 0; nt < 4; ++nt) {
            const s8v bk0 = *reinterpret_cast<const s8v*>(&Ks[(nt * 16 + l15) * LP + qd * 8]);
            const s8v bk1 = *reinterpret_cast<const s8v*>(&Ks[(nt * 16 + l15) * LP + 32 + qd * 8]);
            f4v zz = (f4v){0.f, 0.f, 0.f, 0.f};
            zz = __builtin_amdgcn_mfma_f32_16x16x32_bf16(aq0, bk0, zz, 0, 0, 0);
            sc4[nt] = __builtin_amdgcn_mfma_f32_16x16x32_bf16(aq1, bk1, zz, 0, 0, 0);
        }

        // ---- online softmax per q-row (row r spread across the 16 lanes of this quad)
        #pragma unroll
        for (int r = 0; r < 4; ++r) {
            float v0 = sc4[0][r] * 0.125f, v1 = sc4[1][r] * 0.125f;
            float v2 = sc4[2][r] * 0.125f, v3 = sc4[3][r] * 0.125f;
            float tmax = fmaxf(fmaxf(v0, v1), fmaxf(v2, v3));
            #pragma unroll
            for (int off = 8; off >= 1; off >>= 1) tmax = fmaxf(tmax, __shfl_xor(tmax, off));
            const float mnew  = fmaxf(m_[r], tmax);
            const float alpha = __expf(m_[r] - mnew);
            const float p0 = __expf(v0 - mnew), p1 = __expf(v1 - mnew);
            const float p2 = __expf(v2 - mnew), p3 = __expf(v3 - mnew);
            float psum = (p0 + p1) + (p2 + p3);
            #pragma unroll
            for (int off = 8; off >= 1; off >>= 1) psum += __shfl_xor(psum, off);
            l_[r] = l_[r] * alpha + psum;
            m_[r] = mnew;
            #pragma unroll
            for (int dt = 0; dt < 4; ++dt) oacc[dt][r] *= alpha;
            const int prow = (wv * 16 + qd * 4 + r) * LP;
            Ps[prow +  0 + l15] = f2b_rne(p0);
            Ps[prow + 16 + l15] = f2b_rne(p1);
            Ps[prow + 32 + l15] = f2b_rne(p2);
            Ps[prow + 48 + l15] = f2b_rne(p3);
        }
        __syncthreads();   // conservative: P C-layout writes visible before A-layout reads

        // ---- O += P @ V : A[m=l15][k] from Ps, B[k][n=l15] = Vs[n][k] (V^T rows)
        const s8v ap0 = *reinterpret_cast<const s8v*>(&Ps[(wv * 16 + l15) * LP + qd * 8]);
        const s8v ap1 = *reinterpret_cast<const s8v*>(&Ps[(wv * 16 + l15) * LP + 32 + qd * 8]);
        #pragma unroll
        for (int dt = 0; dt < 4; ++dt) {
            const s8v bv0 = *reinterpret_cast<const s8v*>(&Vs[(dt * 16 + l15) * LP + qd * 8]);
            const s8v bv1 = *reinterpret_cast<const s8v*>(&Vs[(dt * 16 + l15) * LP + 32 + qd * 8]);
            oacc[dt] = __builtin_amdgcn_mfma_f32_16x16x32_bf16(ap0, bv0, oacc[dt], 0, 0, 0);
            oacc[dt] = __builtin_amdgcn_mfma_f32_16x16x32_bf16(ap1, bv1, oacc[dt], 0, 0, 0);
        }
    }

    // ---- epilogue: C-layout row = qd*4+r, col = dt*16+l15
    #pragma unroll
    for (int r = 0; r < 4; ++r) {
        const int s = q0 + wv * 16 + qd * 4 + r;
        const float inv = 1.0f / l_[r];
        float* __restrict__ dst = CTX + ((size_t)(b * S_ + s)) * HID_ + h * HD_ + l15;
        #pragma unroll
        for (int dt = 0; dt < 4; ++dt) dst[dt * 16] = oacc[dt][r] * inv;
    }
}

// ---------------------------------------------------------------------------
// Kernel 3: output projection. CTX fp32 [4096][1024] @ Wo fp32 + bo -> fp32 out.
// ---------------------------------------------------------------------------
__global__ __launch_bounds__(256) void out_proj_kernel(
    const float* __restrict__ CTX, const float* __restrict__ Wo,
    const float* __restrict__ bo, float* __restrict__ out)
{
    const int n0 = blockIdx.x * 64;
    const int m0 = blockIdx.y * 64;
    const int t  = threadIdx.x;
    const int tx = t & 15, ty = t >> 4;

    __shared__ float As[64][17];
    __shared__ float Bs[16][64];

    float acc[4][4] = {};

    const int ar = t >> 2, ac = (t & 3) * 4;
    const int br = ty,     bc = tx * 4;

    for (int k0 = 0; k0 < HID_; k0 += 16) {
        {
            const float4 f = *reinterpret_cast<const float4*>(
                (const void*)(CTX + (size_t)(m0 + ar) * HID_ + k0 + ac));
            As[ar][ac + 0] = f.x; As[ar][ac + 1] = f.y;
            As[ar][ac + 2] = f.z; As[ar][ac + 3] = f.w;
        }
        {
            const float4 f = *reinterpret_cast<const float4*>(
                (const void*)(Wo + (size_t)(k0 + br) * HID_ + n0 + bc));
            Bs[br][bc + 0] = f.x; Bs[br][bc + 1] = f.y;
            Bs[br][bc + 2] = f.z; Bs[br][bc + 3] = f.w;
        }
        __syncthreads();
        #pragma unroll
        for (int kk = 0; kk < 16; ++kk) {
            float a0 = As[ty * 4 + 0][kk], a1 = As[ty * 4 + 1][kk];
            float a2 = As[ty * 4 + 2][kk], a3 = As[ty * 4 + 3][kk];
            float b0 = Bs[kk][tx * 4 + 0], b1 = Bs[kk][tx * 4 + 1];
            float b2 = Bs[kk][tx * 4 + 2], b3 = Bs[kk][tx * 4 + 3];
            acc[0][0] += a0 * b0; acc[0][1] += a0 * b1; acc[0][2] += a0 * b2; acc[0][3] += a0 * b3;
            acc[1][0] += a1 * b0; acc[1][1] += a1 * b1; acc[1][2] += a1 * b2; acc[1][3] += a1 * b3;
            acc[2][0] += a2 * b0; acc[2][1] += a2 * b1; acc[2][2] += a2 * b2; acc[2][3] += a2 * b3;
            acc[3][0] += a3 * b0; acc[3][1] += a3 * b1; acc[3][2] += a3 * b2; acc[3][3] += a3 * b3;
        }
        __syncthreads();
    }

    float bcol[4];
    {
        const float4 f = *reinterpret_cast<const float4*>(
            (const void*)(bo + n0 + tx * 4));
        bcol[0] = f.x; bcol[1] = f.y; bcol[2] = f.z; bcol[3] = f.w;
    }

    #pragma unroll
    for (int i = 0; i < 4; ++i) {
        const int m = m0 + ty * 4 + i;
        const size_t base = (size_t)m * HID_ + n0 + tx * 4;
        #pragma unroll
        for (int j = 0; j < 4; ++j)
            out[base + j] = acc[i][j] + bcol[j];
    }
}

// ---------------------------------------------------------------------------
extern "C" void kernel_launch(void* const* d_in, const int* in_sizes, int n_in,
                              void* d_out, int out_size, void* d_ws, size_t ws_size,
                              hipStream_t stream)
{
    const float* X  = (const float*)d_in[0];
    const float* Wq = (const float*)d_in[1];
    const float* bq = (const float*)d_in[2];
    const float* Wk = (const float*)d_in[3];
    const float* bk = (const float*)d_in[4];
    const float* Wv = (const float*)d_in[5];
    const float* bv = (const float*)d_in[6];
    const float* Wo = (const float*)d_in[7];
    const float* bo = (const float*)d_in[8];
    float* out = (float*)d_out;

    // ws: Qb,Kb,Vt bf16 (8 MB each) + CTX fp32 (16 MB) = 40 MB
    const size_t QKV = (size_t)B_ * NH_ * S_ * HD_;   // 4,194,304
    bf16* Qb = (bf16*)d_ws;
    bf16* Kb = Qb + QKV;
    bf16* Vt = Kb + QKV;
    float* Cw = (float*)(Vt + QKV);

    proj_qkv_kernel<<<dim3(16, 64, 3), 256, 0, stream>>>(X, Wq, bq, Wk, bk, Wv, bv, Qb, Kb, Vt);
    attn_kernel<<<dim3(S_ / 64, B_ * NH_), 256, 0, stream>>>(Qb, Kb, Vt, Cw);
    out_proj_kernel<<<dim3(16, 64), 256, 0, stream>>>(Cw, Wo, bo, out);
}

// Round 4
// 307.723 us; speedup vs baseline: 4.2009x; 2.2850x over previous
//
#include <hip/hip_runtime.h>
#include <hip/hip_bf16.h>

// Problem constants (fixed by reference)
#define B_   2
#define S_   2048
#define HID_ 1024
#define NH_  16
#define HD_  64
#define LP   72   // attn LDS row stride in bf16 elems

typedef __hip_bfloat16 bf16;
typedef __attribute__((ext_vector_type(8))) short s8v;   // 8 bf16 = 4 VGPR (MFMA A/B frag)
typedef __attribute__((ext_vector_type(4))) float f4v;   // MFMA C/D frag

__device__ __forceinline__ unsigned short f2b_rne(float x) {
    unsigned int u = __float_as_uint(x);
    u += 0x7fffu + ((u >> 16) & 1u);
    return (unsigned short)(u >> 16);
}

__device__ __forceinline__ void gload_lds16(const void* g, void* l) {
    __builtin_amdgcn_global_load_lds(
        (const __attribute__((address_space(1))) void*)g,
        (__attribute__((address_space(3))) void*)l, 16, 0, 0);
}

// ---------------------------------------------------------------------------
// Pre-pass A: X fp32 [4096][1024] -> bf16 same layout. 4 elems/thread.
// ---------------------------------------------------------------------------
__global__ __launch_bounds__(256) void convert_x_kernel(
    const float* __restrict__ X, unsigned short* __restrict__ Xb)
{
    const int i = (blockIdx.x * 256 + threadIdx.x) * 4;
    const float4 f = *reinterpret_cast<const float4*>(X + i);
    ushort4 u;
    u.x = f2b_rne(f.x); u.y = f2b_rne(f.y); u.z = f2b_rne(f.z); u.w = f2b_rne(f.w);
    *reinterpret_cast<ushort4*>(Xb + i) = u;
}

// ---------------------------------------------------------------------------
// Pre-pass B: W fp32 [k][n] -> Wt bf16 [n][k]. 64x64 LDS tile transpose.
// grid (16,16,4): z selects which W.
// ---------------------------------------------------------------------------
__global__ __launch_bounds__(256) void transpose_w_kernel(
    const float* __restrict__ W0, const float* __restrict__ W1,
    const float* __restrict__ W2, const float* __restrict__ W3,
    unsigned short* __restrict__ T0, unsigned short* __restrict__ T1,
    unsigned short* __restrict__ T2, unsigned short* __restrict__ T3)
{
    const int z = blockIdx.z;
    const float* __restrict__ W = (z == 0) ? W0 : (z == 1) ? W1 : (z == 2) ? W2 : W3;
    unsigned short* __restrict__ T = (z == 0) ? T0 : (z == 1) ? T1 : (z == 2) ? T2 : T3;

    __shared__ float Tl[64][65];
    const int n0 = blockIdx.x * 64, k0 = blockIdx.y * 64;
    const int t = threadIdx.x;
    const int rr = t >> 4, c4 = (t & 15) * 4;

    #pragma unroll
    for (int i = 0; i < 4; ++i) {
        const int kr = i * 16 + rr;
        const float4 f = *reinterpret_cast<const float4*>(W + (size_t)(k0 + kr) * HID_ + n0 + c4);
        Tl[c4 + 0][kr] = f.x; Tl[c4 + 1][kr] = f.y;
        Tl[c4 + 2][kr] = f.z; Tl[c4 + 3][kr] = f.w;
    }
    __syncthreads();
    #pragma unroll
    for (int i = 0; i < 4; ++i) {
        const int nr = i * 16 + rr;
        ushort4 u;
        u.x = f2b_rne(Tl[nr][c4 + 0]); u.y = f2b_rne(Tl[nr][c4 + 1]);
        u.z = f2b_rne(Tl[nr][c4 + 2]); u.w = f2b_rne(Tl[nr][c4 + 3]);
        *reinterpret_cast<ushort4*>(T + (size_t)(n0 + nr) * HID_ + k0 + c4) = u;
    }
}

// ---------------------------------------------------------------------------
// Shared MFMA mainloop: 128x128 tile, BK=64, 4 waves 2x2, global_load_lds
// staging with XOR chunk swizzle (pchunk = chunk ^ (row&7)) -> conflict-free
// ds_read_b128 fragment reads. A [m][k], Bt [n][k], both bf16 k-major.
// ---------------------------------------------------------------------------
__device__ __forceinline__ void mfma_mainloop(
    const unsigned short* __restrict__ Ag, const unsigned short* __restrict__ Bg,
    unsigned short* As, unsigned short* Bs,
    int m0, int n0, int t, f4v acc[4][4])
{
    const int w = t >> 6, lane = t & 63;
    const int l15 = lane & 15, qd = lane >> 4;
    const int wm = (w & 1) * 64, wn = (w >> 1) * 64;
    const int srow = w * 8 + (lane >> 3);           // staging row within 32-row group
    const int lc8  = (((lane & 7) ^ (lane >> 3)) * 8);  // swizzled k-chunk source

    for (int k0 = 0; k0 < HID_; k0 += 64) {
        __syncthreads();
        #pragma unroll
        for (int it = 0; it < 4; ++it) {
            const int row = it * 32 + srow;
            const int sb = (it * 256 + w * 64) * 8;   // wave-uniform LDS base (ushorts)
            gload_lds16(Ag + (size_t)(m0 + row) * HID_ + k0 + lc8, As + sb);
            gload_lds16(Bg + (size_t)(n0 + row) * HID_ + k0 + lc8, Bs + sb);
        }
        __syncthreads();
        #pragma unroll
        for (int kc = 0; kc < 2; ++kc) {
            const int p = ((kc * 4 + qd) ^ (l15 & 7)) * 8;
            s8v af[4], bf[4];
            #pragma unroll
            for (int mt = 0; mt < 4; ++mt)
                af[mt] = *reinterpret_cast<const s8v*>(As + (wm + mt * 16 + l15) * 64 + p);
            #pragma unroll
            for (int nt = 0; nt < 4; ++nt)
                bf[nt] = *reinterpret_cast<const s8v*>(Bs + (wn + nt * 16 + l15) * 64 + p);
            #pragma unroll
            for (int mt = 0; mt < 4; ++mt)
                #pragma unroll
                for (int nt = 0; nt < 4; ++nt)
                    acc[mt][nt] = __builtin_amdgcn_mfma_f32_16x16x32_bf16(
                        af[mt], bf[nt], acc[mt][nt], 0, 0, 0);
        }
    }
}

// ---------------------------------------------------------------------------
// Kernel: QKV projection GEMM + bias + axial RoPE epilogue.
// grid (8 n-tiles, 32 m-tiles, z=0/1/2). Q,K -> bf16 [bh][s][64]; V -> [bh][d][s].
// ---------------------------------------------------------------------------
__global__ __launch_bounds__(256) void gemm_qkv_kernel(
    const unsigned short* __restrict__ Xb,
    const unsigned short* __restrict__ Wqt, const unsigned short* __restrict__ Wkt,
    const unsigned short* __restrict__ Wvt,
    const float* __restrict__ bq, const float* __restrict__ bk, const float* __restrict__ bv,
    unsigned short* __restrict__ Qb, unsigned short* __restrict__ Kb,
    unsigned short* __restrict__ Vt)
{
    const int z = blockIdx.z;
    const unsigned short* __restrict__ Bt = (z == 0) ? Wqt : (z == 1) ? Wkt : Wvt;
    const float* __restrict__ bias = (z == 0) ? bq : (z == 1) ? bk : bv;

    const int n0 = blockIdx.x * 128, m0 = blockIdx.y * 128;
    const int t = threadIdx.x;
    const int w = t >> 6, lane = t & 63;
    const int l15 = lane & 15, qd = lane >> 4;
    const int wm = (w & 1) * 64, wn = (w >> 1) * 64;

    __shared__ unsigned short As[128 * 64];
    __shared__ unsigned short Bs[128 * 64];

    f4v acc[4][4];
    #pragma unroll
    for (int mt = 0; mt < 4; ++mt)
        #pragma unroll
        for (int nt = 0; nt < 4; ++nt) acc[mt][nt] = (f4v){0.f, 0.f, 0.f, 0.f};

    mfma_mainloop(Xb, Bt, As, Bs, m0, n0, t, acc);

    #pragma unroll
    for (int nt = 0; nt < 4; ++nt) {
        const int col = n0 + wn + nt * 16 + l15;   // 0..1023
        const int h = col >> 6, d = col & 63;
        const float bsc = bias[col];
        // RoPE per-lane constants: segment, tiled sin/cos index, sign
        const int seg = d / 20;                    // 3 only for tail d>=60
        const int ds  = d - seg * 20;
        const float om   = __expf(-0.9210340372f * (float)(ds % 10));
        const float sign = (d & 1) ? 1.f : -1.f;

        #pragma unroll
        for (int mt = 0; mt < 4; ++mt) {
            const int mbase = m0 + wm + mt * 16 + qd * 4;
            const int b = mbase >> 11;
            const int sbase = mbase & 2047;
            if (z == 2) {
                ushort4 u;
                unsigned short* up = (unsigned short*)&u;
                #pragma unroll
                for (int r = 0; r < 4; ++r) up[r] = f2b_rne(acc[mt][nt][r] + bsc);
                *reinterpret_cast<ushort4*>(
                    Vt + ((size_t)(b * NH_ + h) * HD_ + d) * S_ + sbase) = u;
            } else {
                unsigned short* __restrict__ dst = (z == 0 ? Qb : Kb)
                    + ((size_t)(b * NH_ + h) * S_ + sbase) * HD_ + d;
                #pragma unroll
                for (int r = 0; r < 4; ++r) {
                    const int s = sbase + r;
                    float v = acc[mt][nt][r] + bsc;
                    const float xp = __shfl_xor(v, 1);   // pair partner (d^1) in adjacent lane
                    if (d < 60) {
                        const int rem = s & 255;
                        const float pos = (float)(seg == 0 ? (s >> 8)
                                               : (seg == 1 ? (rem >> 4) : (rem & 15)));
                        const float a = pos * om;
                        float sn, cs;
                        sincosf(a, &sn, &cs);
                        v = v * cs + sign * xp * sn;
                    }
                    dst[(size_t)r * HD_] = f2b_rne(v);
                }
            }
        }
    }
}

// ---------------------------------------------------------------------------
// Kernel: output projection GEMM + bias -> fp32 out. grid (8, 32).
// ---------------------------------------------------------------------------
__global__ __launch_bounds__(256) void gemm_out_kernel(
    const unsigned short* __restrict__ Cb, const unsigned short* __restrict__ Wot,
    const float* __restrict__ bo, float* __restrict__ out)
{
    const int n0 = blockIdx.x * 128, m0 = blockIdx.y * 128;
    const int t = threadIdx.x;
    const int w = t >> 6, lane = t & 63;
    const int l15 = lane & 15, qd = lane >> 4;
    const int wm = (w & 1) * 64, wn = (w >> 1) * 64;

    __shared__ unsigned short As[128 * 64];
    __shared__ unsigned short Bs[128 * 64];

    f4v acc[4][4];
    #pragma unroll
    for (int mt = 0; mt < 4; ++mt)
        #pragma unroll
        for (int nt = 0; nt < 4; ++nt) acc[mt][nt] = (f4v){0.f, 0.f, 0.f, 0.f};

    mfma_mainloop(Cb, Wot, As, Bs, m0, n0, t, acc);

    #pragma unroll
    for (int nt = 0; nt < 4; ++nt) {
        const int col = n0 + wn + nt * 16 + l15;
        const float bsc = bo[col];
        #pragma unroll
        for (int mt = 0; mt < 4; ++mt) {
            const int mbase = m0 + wm + mt * 16 + qd * 4;
            #pragma unroll
            for (int r = 0; r < 4; ++r)
                out[(size_t)(mbase + r) * HID_ + col] = acc[mt][nt][r] + bsc;
        }
    }
}

// ---------------------------------------------------------------------------
// Kernel: MFMA flash attention (unchanged from R3 except CTX -> bf16).
// ---------------------------------------------------------------------------
__global__ __launch_bounds__(256) void attn_kernel(
    const bf16* __restrict__ Qb, const bf16* __restrict__ Kb,
    const bf16* __restrict__ Vt, unsigned short* __restrict__ CTX)
{
    const int q0 = blockIdx.x * 64;
    const int bh = blockIdx.y;
    const int b  = bh >> 4, h = bh & 15;
    const int t  = threadIdx.x;
    const int wv = t >> 6;
    const int ln = t & 63;
    const int l15 = ln & 15, qd = ln >> 4;

    __shared__ unsigned short Ks[64 * LP];   // [k_local][d]
    __shared__ unsigned short Vs[64 * LP];   // [d][k_local]   (V^T tile)
    __shared__ unsigned short Ps[64 * LP];   // [q_local][k_local]

    const bf16* Qrow = Qb + ((size_t)bh * S_ + q0 + wv * 16 + l15) * HD_ + qd * 8;
    const s8v aq0 = *reinterpret_cast<const s8v*>(Qrow);
    const s8v aq1 = *reinterpret_cast<const s8v*>(Qrow + 32);

    f4v oacc[4];
    float m_[4], l_[4];
    #pragma unroll
    for (int r = 0; r < 4; ++r) {
        m_[r] = -1e30f; l_[r] = 0.f;
        oacc[r] = (f4v){0.f, 0.f, 0.f, 0.f};
    }

    const bf16* __restrict__ Kg = Kb + (size_t)bh * S_ * HD_;
    const bf16* __restrict__ Vg = Vt + (size_t)bh * HD_ * S_;

    const int sr = t >> 3;
    const int sc = (t & 7) * 8;

    for (int k0 = 0; k0 < S_; k0 += 64) {
        __syncthreads();
        *reinterpret_cast<s8v*>(&Ks[sr * LP + sc]) =
            *reinterpret_cast<const s8v*>(Kg + (size_t)(k0 + sr) * HD_ + sc);
        *reinterpret_cast<s8v*>(&Ks[(sr + 32) * LP + sc]) =
            *reinterpret_cast<const s8v*>(Kg + (size_t)(k0 + sr + 32) * HD_ + sc);
        *reinterpret_cast<s8v*>(&Vs[sr * LP + sc]) =
            *reinterpret_cast<const s8v*>(Vg + (size_t)sr * S_ + k0 + sc);
        *reinterpret_cast<s8v*>(&Vs[(sr + 32) * LP + sc]) =
            *reinterpret_cast<const s8v*>(Vg + (size_t)(sr + 32) * S_ + k0 + sc);
        __syncthreads();

        f4v sc4[4];
        #pragma unroll
        for (int nt = 0; nt < 4; ++nt) {
            const s8v bk0 = *reinterpret_cast<const s8v*>(&Ks[(nt * 16 + l15) * LP + qd * 8]);
            const s8v bk1 = *reinterpret_cast<const s8v*>(&Ks[(nt * 16 + l15) * LP + 32 + qd * 8]);
            f4v zz = (f4v){0.f, 0.f, 0.f, 0.f};
            zz = __builtin_amdgcn_mfma_f32_16x16x32_bf16(aq0, bk0, zz, 0, 0, 0);
            sc4[nt] = __builtin_amdgcn_mfma_f32_16x16x32_bf16(aq1, bk1, zz, 0, 0, 0);
        }

        #pragma unroll
        for (int r = 0; r < 4; ++r) {
            float v0 = sc4[0][r] * 0.125f, v1 = sc4[1][r] * 0.125f;
            float v2 = sc4[2][r] * 0.125f, v3 = sc4[3][r] * 0.125f;
            float tmax = fmaxf(fmaxf(v0, v1), fmaxf(v2, v3));
            #pragma unroll
            for (int off = 8; off >= 1; off >>= 1) tmax = fmaxf(tmax, __shfl_xor(tmax, off));
            const float mnew  = fmaxf(m_[r], tmax);
            const float alpha = __expf(m_[r] - mnew);
            const float p0 = __expf(v0 - mnew), p1 = __expf(v1 - mnew);
            const float p2 = __expf(v2 - mnew), p3 = __expf(v3 - mnew);
            float psum = (p0 + p1) + (p2 + p3);
            #pragma unroll
            for (int off = 8; off >= 1; off >>= 1) psum += __shfl_xor(psum, off);
            l_[r] = l_[r] * alpha + psum;
            m_[r] = mnew;
            #pragma unroll
            for (int dt = 0; dt < 4; ++dt) oacc[dt][r] *= alpha;
            const int prow = (wv * 16 + qd * 4 + r) * LP;
            Ps[prow +  0 + l15] = f2b_rne(p0);
            Ps[prow + 16 + l15] = f2b_rne(p1);
            Ps[prow + 32 + l15] = f2b_rne(p2);
            Ps[prow + 48 + l15] = f2b_rne(p3);
        }
        __syncthreads();

        const s8v ap0 = *reinterpret_cast<const s8v*>(&Ps[(wv * 16 + l15) * LP + qd * 8]);
        const s8v ap1 = *reinterpret_cast<const s8v*>(&Ps[(wv * 16 + l15) * LP + 32 + qd * 8]);
        #pragma unroll
        for (int dt = 0; dt < 4; ++dt) {
            const s8v bv0 = *reinterpret_cast<const s8v*>(&Vs[(dt * 16 + l15) * LP + qd * 8]);
            const s8v bv1 = *reinterpret_cast<const s8v*>(&Vs[(dt * 16 + l15) * LP + 32 + qd * 8]);
            oacc[dt] = __builtin_amdgcn_mfma_f32_16x16x32_bf16(ap0, bv0, oacc[dt], 0, 0, 0);
            oacc[dt] = __builtin_amdgcn_mfma_f32_16x16x32_bf16(ap1, bv1, oacc[dt], 0, 0, 0);
        }
    }

    #pragma unroll
    for (int r = 0; r < 4; ++r) {
        const int s = q0 + wv * 16 + qd * 4 + r;
        const float inv = 1.0f / l_[r];
        unsigned short* __restrict__ dst = CTX + ((size_t)(b * S_ + s)) * HID_ + h * HD_ + l15;
        #pragma unroll
        for (int dt = 0; dt < 4; ++dt) dst[dt * 16] = f2b_rne(oacc[dt][r] * inv);
    }
}

// ---------------------------------------------------------------------------
extern "C" void kernel_launch(void* const* d_in, const int* in_sizes, int n_in,
                              void* d_out, int out_size, void* d_ws, size_t ws_size,
                              hipStream_t stream)
{
    const float* X  = (const float*)d_in[0];
    const float* Wq = (const float*)d_in[1];
    const float* bq = (const float*)d_in[2];
    const float* Wk = (const float*)d_in[3];
    const float* bk = (const float*)d_in[4];
    const float* Wv = (const float*)d_in[5];
    const float* bv = (const float*)d_in[6];
    const float* Wo = (const float*)d_in[7];
    const float* bo = (const float*)d_in[8];
    float* out = (float*)d_out;

    // ws layout (bf16 elems unless noted):
    // Xb 4M | Wqt 1M | Wkt 1M | Wvt 1M | Wot 1M | Qb 4M | Kb 4M | Vt 4M | Cb 4M  = 48 MB
    const size_t QKV = (size_t)B_ * NH_ * S_ * HD_;   // 4,194,304
    unsigned short* Xb  = (unsigned short*)d_ws;
    unsigned short* Wqt = Xb  + QKV;
    unsigned short* Wkt = Wqt + (size_t)HID_ * HID_;
    unsigned short* Wvt = Wkt + (size_t)HID_ * HID_;
    unsigned short* Wot = Wvt + (size_t)HID_ * HID_;
    unsigned short* Qb  = Wot + (size_t)HID_ * HID_;
    unsigned short* Kb  = Qb + QKV;
    unsigned short* Vt  = Kb + QKV;
    unsigned short* Cb  = Vt + QKV;

    convert_x_kernel<<<4096, 256, 0, stream>>>(X, Xb);
    transpose_w_kernel<<<dim3(16, 16, 4), 256, 0, stream>>>(
        Wq, Wk, Wv, Wo, Wqt, Wkt, Wvt, Wot);
    gemm_qkv_kernel<<<dim3(8, 32, 3), 256, 0, stream>>>(
        Xb, Wqt, Wkt, Wvt, bq, bk, bv, Qb, Kb, Vt);
    attn_kernel<<<dim3(S_ / 64, B_ * NH_), 256, 0, stream>>>(
        (const bf16*)Qb, (const bf16*)Kb, (const bf16*)Vt, Cb);
    gemm_out_kernel<<<dim3(8, 32), 256, 0, stream>>>(Cb, Wot, bo, out);
}

// Round 5
// 243.200 us; speedup vs baseline: 5.3154x; 1.2653x over previous
//
#include <hip/hip_runtime.h>
#include <hip/hip_bf16.h>

// Problem constants (fixed by reference)
#define B_   2
#define S_   2048
#define HID_ 1024
#define NH_  16
#define HD_  64

typedef __hip_bfloat16 bf16;
typedef __attribute__((ext_vector_type(8))) short s8v;   // 8 bf16 = 4 VGPR (MFMA A/B frag)
typedef __attribute__((ext_vector_type(4))) float f4v;   // MFMA C/D frag

// Q pre-scale: 0.125 (1/sqrt(64)) * log2(e) -> exp2(score) == exp(q.k/8) exactly
#define QSCALE 0.18033688011112042f

__device__ __forceinline__ unsigned short f2b_rne(float x) {
    unsigned int u = __float_as_uint(x);
    u += 0x7fffu + ((u >> 16) & 1u);
    return (unsigned short)(u >> 16);
}

__device__ __forceinline__ void gload_lds16(const void* g, void* l) {
    __builtin_amdgcn_global_load_lds(
        (const __attribute__((address_space(1))) void*)g,
        (__attribute__((address_space(3))) void*)l, 16, 0, 0);
}

// ---------------------------------------------------------------------------
// Pre-pass A: X fp32 [4096][1024] -> bf16 same layout. 4 elems/thread.
// ---------------------------------------------------------------------------
__global__ __launch_bounds__(256) void convert_x_kernel(
    const float* __restrict__ X, unsigned short* __restrict__ Xb)
{
    const int i = (blockIdx.x * 256 + threadIdx.x) * 4;
    const float4 f = *reinterpret_cast<const float4*>(X + i);
    ushort4 u;
    u.x = f2b_rne(f.x); u.y = f2b_rne(f.y); u.z = f2b_rne(f.z); u.w = f2b_rne(f.w);
    *reinterpret_cast<ushort4*>(Xb + i) = u;
}

// ---------------------------------------------------------------------------
// Pre-pass B: W fp32 [k][n] -> Wt bf16 [n][k]. 64x64 LDS tile transpose.
// ---------------------------------------------------------------------------
__global__ __launch_bounds__(256) void transpose_w_kernel(
    const float* __restrict__ W0, const float* __restrict__ W1,
    const float* __restrict__ W2, const float* __restrict__ W3,
    unsigned short* __restrict__ T0, unsigned short* __restrict__ T1,
    unsigned short* __restrict__ T2, unsigned short* __restrict__ T3)
{
    const int z = blockIdx.z;
    const float* __restrict__ W = (z == 0) ? W0 : (z == 1) ? W1 : (z == 2) ? W2 : W3;
    unsigned short* __restrict__ T = (z == 0) ? T0 : (z == 1) ? T1 : (z == 2) ? T2 : T3;

    __shared__ float Tl[64][65];
    const int n0 = blockIdx.x * 64, k0 = blockIdx.y * 64;
    const int t = threadIdx.x;
    const int rr = t >> 4, c4 = (t & 15) * 4;

    #pragma unroll
    for (int i = 0; i < 4; ++i) {
        const int kr = i * 16 + rr;
        const float4 f = *reinterpret_cast<const float4*>(W + (size_t)(k0 + kr) * HID_ + n0 + c4);
        Tl[c4 + 0][kr] = f.x; Tl[c4 + 1][kr] = f.y;
        Tl[c4 + 2][kr] = f.z; Tl[c4 + 3][kr] = f.w;
    }
    __syncthreads();
    #pragma unroll
    for (int i = 0; i < 4; ++i) {
        const int nr = i * 16 + rr;
        ushort4 u;
        u.x = f2b_rne(Tl[nr][c4 + 0]); u.y = f2b_rne(Tl[nr][c4 + 1]);
        u.z = f2b_rne(Tl[nr][c4 + 2]); u.w = f2b_rne(Tl[nr][c4 + 3]);
        *reinterpret_cast<ushort4*>(T + (size_t)(n0 + nr) * HID_ + k0 + c4) = u;
    }
}

// ---------------------------------------------------------------------------
// Shared MFMA mainloop: 128x128 tile, BK=64, 4 waves 2x2, global_load_lds
// staging with XOR chunk swizzle. A [m][k], Bt [n][k], both bf16 k-major.
// ---------------------------------------------------------------------------
__device__ __forceinline__ void mfma_mainloop(
    const unsigned short* __restrict__ Ag, const unsigned short* __restrict__ Bg,
    unsigned short* As, unsigned short* Bs,
    int m0, int n0, int t, f4v acc[4][4])
{
    const int w = t >> 6, lane = t & 63;
    const int l15 = lane & 15, qd = lane >> 4;
    const int wm = (w & 1) * 64, wn = (w >> 1) * 64;
    const int srow = w * 8 + (lane >> 3);
    const int lc8  = (((lane & 7) ^ (lane >> 3)) * 8);

    for (int k0 = 0; k0 < HID_; k0 += 64) {
        __syncthreads();
        #pragma unroll
        for (int it = 0; it < 4; ++it) {
            const int row = it * 32 + srow;
            const int sb = (it * 256 + w * 64) * 8;
            gload_lds16(Ag + (size_t)(m0 + row) * HID_ + k0 + lc8, As + sb);
            gload_lds16(Bg + (size_t)(n0 + row) * HID_ + k0 + lc8, Bs + sb);
        }
        __syncthreads();
        #pragma unroll
        for (int kc = 0; kc < 2; ++kc) {
            const int p = ((kc * 4 + qd) ^ (l15 & 7)) * 8;
            s8v af[4], bf[4];
            #pragma unroll
            for (int mt = 0; mt < 4; ++mt)
                af[mt] = *reinterpret_cast<const s8v*>(As + (wm + mt * 16 + l15) * 64 + p);
            #pragma unroll
            for (int nt = 0; nt < 4; ++nt)
                bf[nt] = *reinterpret_cast<const s8v*>(Bs + (wn + nt * 16 + l15) * 64 + p);
            #pragma unroll
            for (int mt = 0; mt < 4; ++mt)
                #pragma unroll
                for (int nt = 0; nt < 4; ++nt)
                    acc[mt][nt] = __builtin_amdgcn_mfma_f32_16x16x32_bf16(
                        af[mt], bf[nt], acc[mt][nt], 0, 0, 0);
        }
    }
}

// ---------------------------------------------------------------------------
// Kernel: QKV projection GEMM + bias + axial RoPE epilogue.
// Q is additionally pre-scaled by QSCALE (softmax exp2 fold).
// ---------------------------------------------------------------------------
__global__ __launch_bounds__(256) void gemm_qkv_kernel(
    const unsigned short* __restrict__ Xb,
    const unsigned short* __restrict__ Wqt, const unsigned short* __restrict__ Wkt,
    const unsigned short* __restrict__ Wvt,
    const float* __restrict__ bq, const float* __restrict__ bk, const float* __restrict__ bv,
    unsigned short* __restrict__ Qb, unsigned short* __restrict__ Kb,
    unsigned short* __restrict__ Vt)
{
    const int z = blockIdx.z;
    const unsigned short* __restrict__ Bt = (z == 0) ? Wqt : (z == 1) ? Wkt : Wvt;
    const float* __restrict__ bias = (z == 0) ? bq : (z == 1) ? bk : bv;

    const int n0 = blockIdx.x * 128, m0 = blockIdx.y * 128;
    const int t = threadIdx.x;
    const int w = t >> 6, lane = t & 63;
    const int l15 = lane & 15, qd = lane >> 4;
    const int wm = (w & 1) * 64, wn = (w >> 1) * 64;

    __shared__ unsigned short As[128 * 64];
    __shared__ unsigned short Bs[128 * 64];

    f4v acc[4][4];
    #pragma unroll
    for (int mt = 0; mt < 4; ++mt)
        #pragma unroll
        for (int nt = 0; nt < 4; ++nt) acc[mt][nt] = (f4v){0.f, 0.f, 0.f, 0.f};

    mfma_mainloop(Xb, Bt, As, Bs, m0, n0, t, acc);

    const float osc = (z == 0) ? QSCALE : 1.f;

    #pragma unroll
    for (int nt = 0; nt < 4; ++nt) {
        const int col = n0 + wn + nt * 16 + l15;   // 0..1023
        const int h = col >> 6, d = col & 63;
        const float bsc = bias[col];
        const int seg = d / 20;
        const int ds  = d - seg * 20;
        const float om   = __expf(-0.9210340372f * (float)(ds % 10));
        const float sign = (d & 1) ? 1.f : -1.f;

        #pragma unroll
        for (int mt = 0; mt < 4; ++mt) {
            const int mbase = m0 + wm + mt * 16 + qd * 4;
            const int b = mbase >> 11;
            const int sbase = mbase & 2047;
            if (z == 2) {
                ushort4 u;
                unsigned short* up = (unsigned short*)&u;
                #pragma unroll
                for (int r = 0; r < 4; ++r) up[r] = f2b_rne(acc[mt][nt][r] + bsc);
                *reinterpret_cast<ushort4*>(
                    Vt + ((size_t)(b * NH_ + h) * HD_ + d) * S_ + sbase) = u;
            } else {
                unsigned short* __restrict__ dst = (z == 0 ? Qb : Kb)
                    + ((size_t)(b * NH_ + h) * S_ + sbase) * HD_ + d;
                #pragma unroll
                for (int r = 0; r < 4; ++r) {
                    const int s = sbase + r;
                    float v = acc[mt][nt][r] + bsc;
                    const float xp = __shfl_xor(v, 1);
                    if (d < 60) {
                        const int rem = s & 255;
                        const float pos = (float)(seg == 0 ? (s >> 8)
                                               : (seg == 1 ? (rem >> 4) : (rem & 15)));
                        const float a = pos * om;
                        float sn, cs;
                        sincosf(a, &sn, &cs);
                        v = v * cs + sign * xp * sn;
                    }
                    dst[(size_t)r * HD_] = f2b_rne(v * osc);
                }
            }
        }
    }
}

// ---------------------------------------------------------------------------
// Kernel: output projection GEMM + bias -> fp32 out. grid (8, 32).
// ---------------------------------------------------------------------------
__global__ __launch_bounds__(256) void gemm_out_kernel(
    const unsigned short* __restrict__ Cb, const unsigned short* __restrict__ Wot,
    const float* __restrict__ bo, float* __restrict__ out)
{
    const int n0 = blockIdx.x * 128, m0 = blockIdx.y * 128;
    const int t = threadIdx.x;
    const int w = t >> 6, lane = t & 63;
    const int l15 = lane & 15, qd = lane >> 4;
    const int wm = (w & 1) * 64, wn = (w >> 1) * 64;

    __shared__ unsigned short As[128 * 64];
    __shared__ unsigned short Bs[128 * 64];

    f4v acc[4][4];
    #pragma unroll
    for (int mt = 0; mt < 4; ++mt)
        #pragma unroll
        for (int nt = 0; nt < 4; ++nt) acc[mt][nt] = (f4v){0.f, 0.f, 0.f, 0.f};

    mfma_mainloop(Cb, Wot, As, Bs, m0, n0, t, acc);

    #pragma unroll
    for (int nt = 0; nt < 4; ++nt) {
        const int col = n0 + wn + nt * 16 + l15;
        const float bsc = bo[col];
        #pragma unroll
        for (int mt = 0; mt < 4; ++mt) {
            const int mbase = m0 + wm + mt * 16 + qd * 4;
            #pragma unroll
            for (int r = 0; r < 4; ++r)
                out[(size_t)(mbase + r) * HID_ + col] = acc[mt][nt][r] + bsc;
        }
    }
}

// ---------------------------------------------------------------------------
// Kernel: MFMA flash attention, fixed-max softmax (exp2-folded), k-tile 128.
// Block = 4 waves; wave w owns q rows [w*16, w*16+16). K,V staged via
// global_load_lds with XOR chunk swizzle; P is per-wave private (no barrier).
//   scores: 8 n-tiles x 2 d-chunks of mfma (Q pre-scaled by QSCALE)
//   p = exp2(score) -> Ps (bf16); l accumulated as per-lane partials
//   PV: 4 k-chunks x 4 d-tiles; l reduced once at epilogue.
// ---------------------------------------------------------------------------
__global__ __launch_bounds__(256, 3) void attn_kernel(
    const bf16* __restrict__ Qb, const bf16* __restrict__ Kb,
    const bf16* __restrict__ Vt, unsigned short* __restrict__ CTX)
{
    const int q0 = blockIdx.x * 64;
    const int bh = blockIdx.y;
    const int b  = bh >> 4, h = bh & 15;
    const int t  = threadIdx.x;
    const int w  = t >> 6;
    const int lane = t & 63;
    const int l15 = lane & 15, qd = lane >> 4;

    __shared__ unsigned short Ks[128 * 64];   // [k_local][d], chunk-swizzled by row&7
    __shared__ unsigned short Vs[64 * 128];   // [d][k_local], chunk-swizzled by row&15
    __shared__ unsigned short Ps[64 * 136];   // [q_local][k_local], padded, per-wave rows

    // Q A-fragments once (pre-scaled by QSCALE in projection epilogue)
    const bf16* Qrow = Qb + ((size_t)bh * S_ + q0 + w * 16 + l15) * HD_ + qd * 8;
    const s8v aq0 = *reinterpret_cast<const s8v*>(Qrow);
    const s8v aq1 = *reinterpret_cast<const s8v*>(Qrow + 32);

    f4v oacc[4];
    float lacc[4];
    #pragma unroll
    for (int r = 0; r < 4; ++r) {
        lacc[r] = 0.f;
        oacc[r] = (f4v){0.f, 0.f, 0.f, 0.f};
    }

    const bf16* __restrict__ Kg = Kb + (size_t)bh * S_ * HD_;
    const bf16* __restrict__ Vg = Vt + (size_t)bh * HD_ * S_;

    const int krow = lane >> 3;                     // 0..7
    const int ksw  = ((lane & 7) ^ krow) * 8;       // K source chunk swizzle
    const int vrow = lane >> 4;                     // 0..3

    for (int k0 = 0; k0 < S_; k0 += 128) {
        __syncthreads();   // all waves done reading Ks/Vs from previous tile
        #pragma unroll
        for (int it = 0; it < 4; ++it) {
            gload_lds16(Kg + (size_t)(k0 + w * 32 + it * 8 + krow) * HD_ + ksw,
                        Ks + (w * 32 + it * 8) * 64);
        }
        #pragma unroll
        for (int it = 0; it < 4; ++it) {
            const int r = w * 16 + it * 4 + vrow;   // d row
            const int sv = ((lane & 15) ^ ((it * 4 + vrow) & 15)) * 8;
            gload_lds16(Vg + (size_t)r * S_ + k0 + sv,
                        Vs + (w * 16 + it * 4) * 128);
        }
        __syncthreads();   // staging visible (compiler drains vmcnt before barrier)

        // ---- scores: sc_[nt] = S^(tile)[q=qd*4+r][k=nt*16+l15]
        f4v sc_[8];
        #pragma unroll
        for (int nt = 0; nt < 8; ++nt) {
            const int row = nt * 16 + l15;
            const unsigned short* kr = Ks + row * 64;
            const s8v b0 = *reinterpret_cast<const s8v*>(kr + ((qd ^ (l15 & 7)) * 8));
            const s8v b1 = *reinterpret_cast<const s8v*>(kr + (((qd + 4) ^ (l15 & 7)) * 8));
            f4v z = (f4v){0.f, 0.f, 0.f, 0.f};
            z = __builtin_amdgcn_mfma_f32_16x16x32_bf16(aq0, b0, z, 0, 0, 0);
            sc_[nt] = __builtin_amdgcn_mfma_f32_16x16x32_bf16(aq1, b1, z, 0, 0, 0);
        }

        // ---- p = exp2(score); accumulate l partials; P -> LDS (per-wave rows)
        #pragma unroll
        for (int nt = 0; nt < 8; ++nt) {
            #pragma unroll
            for (int r = 0; r < 4; ++r) {
                const float p = __builtin_amdgcn_exp2f(sc_[nt][r]);
                lacc[r] += p;
                Ps[(w * 16 + qd * 4 + r) * 136 + nt * 16 + l15] = f2b_rne(p);
            }
        }
        // no barrier: wave w writes and reads only rows w*16..w*16+15

        // ---- O += P @ V
        #pragma unroll
        for (int kc = 0; kc < 4; ++kc) {
            const s8v ap = *reinterpret_cast<const s8v*>(
                Ps + (w * 16 + l15) * 136 + kc * 32 + qd * 8);
            #pragma unroll
            for (int dt = 0; dt < 4; ++dt) {
                const int vr = dt * 16 + l15;
                const s8v bv = *reinterpret_cast<const s8v*>(
                    Vs + vr * 128 + (((kc * 4 + qd) ^ l15) & 15) * 8);
                oacc[dt] = __builtin_amdgcn_mfma_f32_16x16x32_bf16(ap, bv, oacc[dt], 0, 0, 0);
            }
        }
    }

    // ---- epilogue: reduce l across the 16 lanes sharing this quad, store O/l
    #pragma unroll
    for (int r = 0; r < 4; ++r) {
        float lsum = lacc[r];
        #pragma unroll
        for (int off = 8; off >= 1; off >>= 1) lsum += __shfl_xor(lsum, off);
        const float inv = 1.0f / lsum;
        const int s = q0 + w * 16 + qd * 4 + r;
        unsigned short* __restrict__ dst = CTX + ((size_t)(b * S_ + s)) * HID_ + h * HD_ + l15;
        #pragma unroll
        for (int dt = 0; dt < 4; ++dt) dst[dt * 16] = f2b_rne(oacc[dt][r] * inv);
    }
}

// ---------------------------------------------------------------------------
extern "C" void kernel_launch(void* const* d_in, const int* in_sizes, int n_in,
                              void* d_out, int out_size, void* d_ws, size_t ws_size,
                              hipStream_t stream)
{
    const float* X  = (const float*)d_in[0];
    const float* Wq = (const float*)d_in[1];
    const float* bq = (const float*)d_in[2];
    const float* Wk = (const float*)d_in[3];
    const float* bk = (const float*)d_in[4];
    const float* Wv = (const float*)d_in[5];
    const float* bv = (const float*)d_in[6];
    const float* Wo = (const float*)d_in[7];
    const float* bo = (const float*)d_in[8];
    float* out = (float*)d_out;

    // ws: Xb 4M | Wqt 1M | Wkt 1M | Wvt 1M | Wot 1M | Qb 4M | Kb 4M | Vt 4M | Cb 4M (bf16) = 48 MB
    const size_t QKV = (size_t)B_ * NH_ * S_ * HD_;   // 4,194,304
    unsigned short* Xb  = (unsigned short*)d_ws;
    unsigned short* Wqt = Xb  + QKV;
    unsigned short* Wkt = Wqt + (size_t)HID_ * HID_;
    unsigned short* Wvt = Wkt + (size_t)HID_ * HID_;
    unsigned short* Wot = Wvt + (size_t)HID_ * HID_;
    unsigned short* Qb  = Wot + (size_t)HID_ * HID_;
    unsigned short* Kb  = Qb + QKV;
    unsigned short* Vt  = Kb + QKV;
    unsigned short* Cb  = Vt + QKV;

    convert_x_kernel<<<4096, 256, 0, stream>>>(X, Xb);
    transpose_w_kernel<<<dim3(16, 16, 4), 256, 0, stream>>>(
        Wq, Wk, Wv, Wo, Wqt, Wkt, Wvt, Wot);
    gemm_qkv_kernel<<<dim3(8, 32, 3), 256, 0, stream>>>(
        Xb, Wqt, Wkt, Wvt, bq, bk, bv, Qb, Kb, Vt);
    attn_kernel<<<dim3(S_ / 64, B_ * NH_), 256, 0, stream>>>(
        (const bf16*)Qb, (const bf16*)Kb, (const bf16*)Vt, Cb);
    gemm_out_kernel<<<dim3(8, 32), 256, 0, stream>>>(Cb, Wot, bo, out);
}

// Round 6
// 208.334 us; speedup vs baseline: 6.2050x; 1.1674x over previous
//
#include <hip/hip_runtime.h>
#include <hip/hip_bf16.h>

// Problem constants (fixed by reference)
#define B_   2
#define S_   2048
#define HID_ 1024
#define NH_  16
#define HD_  64

typedef __hip_bfloat16 bf16;
typedef __attribute__((ext_vector_type(8))) short s8v;   // 8 bf16 = 4 VGPR (MFMA A/B frag)
typedef __attribute__((ext_vector_type(4))) float f4v;   // MFMA C/D frag

// Q pre-scale: 0.125 (1/sqrt(64)) * log2(e) -> exp2(score) == exp(q.k/8) exactly
#define QSCALE 0.18033688011112042f

__device__ __forceinline__ unsigned short f2b_rne(float x) {
    unsigned int u = __float_as_uint(x);
    u += 0x7fffu + ((u >> 16) & 1u);
    return (unsigned short)(u >> 16);
}

__device__ __forceinline__ void gload_lds16(const void* g, void* l) {
    __builtin_amdgcn_global_load_lds(
        (const __attribute__((address_space(1))) void*)g,
        (__attribute__((address_space(3))) void*)l, 16, 0, 0);
}

// ---------------------------------------------------------------------------
// Pre-pass A: X fp32 [4096][1024] -> bf16 same layout. 4 elems/thread.
// ---------------------------------------------------------------------------
__global__ __launch_bounds__(256) void convert_x_kernel(
    const float* __restrict__ X, unsigned short* __restrict__ Xb)
{
    const int i = (blockIdx.x * 256 + threadIdx.x) * 4;
    const float4 f = *reinterpret_cast<const float4*>(X + i);
    ushort4 u;
    u.x = f2b_rne(f.x); u.y = f2b_rne(f.y); u.z = f2b_rne(f.z); u.w = f2b_rne(f.w);
    *reinterpret_cast<ushort4*>(Xb + i) = u;
}

// ---------------------------------------------------------------------------
// Pre-pass B: W fp32 [k][n] -> Wt bf16 [n][k]. 64x64 LDS tile transpose.
// ---------------------------------------------------------------------------
__global__ __launch_bounds__(256) void transpose_w_kernel(
    const float* __restrict__ W0, const float* __restrict__ W1,
    const float* __restrict__ W2, const float* __restrict__ W3,
    unsigned short* __restrict__ T0, unsigned short* __restrict__ T1,
    unsigned short* __restrict__ T2, unsigned short* __restrict__ T3)
{
    const int z = blockIdx.z;
    const float* __restrict__ W = (z == 0) ? W0 : (z == 1) ? W1 : (z == 2) ? W2 : W3;
    unsigned short* __restrict__ T = (z == 0) ? T0 : (z == 1) ? T1 : (z == 2) ? T2 : T3;

    __shared__ float Tl[64][65];
    const int n0 = blockIdx.x * 64, k0 = blockIdx.y * 64;
    const int t = threadIdx.x;
    const int rr = t >> 4, c4 = (t & 15) * 4;

    #pragma unroll
    for (int i = 0; i < 4; ++i) {
        const int kr = i * 16 + rr;
        const float4 f = *reinterpret_cast<const float4*>(W + (size_t)(k0 + kr) * HID_ + n0 + c4);
        Tl[c4 + 0][kr] = f.x; Tl[c4 + 1][kr] = f.y;
        Tl[c4 + 2][kr] = f.z; Tl[c4 + 3][kr] = f.w;
    }
    __syncthreads();
    #pragma unroll
    for (int i = 0; i < 4; ++i) {
        const int nr = i * 16 + rr;
        ushort4 u;
        u.x = f2b_rne(Tl[nr][c4 + 0]); u.y = f2b_rne(Tl[nr][c4 + 1]);
        u.z = f2b_rne(Tl[nr][c4 + 2]); u.w = f2b_rne(Tl[nr][c4 + 3]);
        *reinterpret_cast<ushort4*>(T + (size_t)(n0 + nr) * HID_ + k0 + c4) = u;
    }
}

// ---------------------------------------------------------------------------
// Shared MFMA mainloop: 128x128 tile, BK=64, 4 waves 2x2, global_load_lds
// staging with XOR chunk swizzle. A [m][k], Bt [n][k], both bf16 k-major.
// ---------------------------------------------------------------------------
__device__ __forceinline__ void mfma_mainloop(
    const unsigned short* __restrict__ Ag, const unsigned short* __restrict__ Bg,
    unsigned short* As, unsigned short* Bs,
    int m0, int n0, int t, f4v acc[4][4])
{
    const int w = t >> 6, lane = t & 63;
    const int l15 = lane & 15, qd = lane >> 4;
    const int wm = (w & 1) * 64, wn = (w >> 1) * 64;
    const int srow = w * 8 + (lane >> 3);
    const int lc8  = (((lane & 7) ^ (lane >> 3)) * 8);

    for (int k0 = 0; k0 < HID_; k0 += 64) {
        __syncthreads();
        #pragma unroll
        for (int it = 0; it < 4; ++it) {
            const int row = it * 32 + srow;
            const int sb = (it * 256 + w * 64) * 8;
            gload_lds16(Ag + (size_t)(m0 + row) * HID_ + k0 + lc8, As + sb);
            gload_lds16(Bg + (size_t)(n0 + row) * HID_ + k0 + lc8, Bs + sb);
        }
        __syncthreads();
        #pragma unroll
        for (int kc = 0; kc < 2; ++kc) {
            const int p = ((kc * 4 + qd) ^ (l15 & 7)) * 8;
            s8v af[4], bf[4];
            #pragma unroll
            for (int mt = 0; mt < 4; ++mt)
                af[mt] = *reinterpret_cast<const s8v*>(As + (wm + mt * 16 + l15) * 64 + p);
            #pragma unroll
            for (int nt = 0; nt < 4; ++nt)
                bf[nt] = *reinterpret_cast<const s8v*>(Bs + (wn + nt * 16 + l15) * 64 + p);
            #pragma unroll
            for (int mt = 0; mt < 4; ++mt)
                #pragma unroll
                for (int nt = 0; nt < 4; ++nt)
                    acc[mt][nt] = __builtin_amdgcn_mfma_f32_16x16x32_bf16(
                        af[mt], bf[nt], acc[mt][nt], 0, 0, 0);
        }
    }
}

// ---------------------------------------------------------------------------
// Kernel: QKV projection GEMM + bias + axial RoPE epilogue.
// Q is additionally pre-scaled by QSCALE (softmax exp2 fold).
// ---------------------------------------------------------------------------
__global__ __launch_bounds__(256) void gemm_qkv_kernel(
    const unsigned short* __restrict__ Xb,
    const unsigned short* __restrict__ Wqt, const unsigned short* __restrict__ Wkt,
    const unsigned short* __restrict__ Wvt,
    const float* __restrict__ bq, const float* __restrict__ bk, const float* __restrict__ bv,
    unsigned short* __restrict__ Qb, unsigned short* __restrict__ Kb,
    unsigned short* __restrict__ Vt)
{
    const int z = blockIdx.z;
    const unsigned short* __restrict__ Bt = (z == 0) ? Wqt : (z == 1) ? Wkt : Wvt;
    const float* __restrict__ bias = (z == 0) ? bq : (z == 1) ? bk : bv;

    const int n0 = blockIdx.x * 128, m0 = blockIdx.y * 128;
    const int t = threadIdx.x;
    const int w = t >> 6, lane = t & 63;
    const int l15 = lane & 15, qd = lane >> 4;
    const int wm = (w & 1) * 64, wn = (w >> 1) * 64;

    __shared__ unsigned short As[128 * 64];
    __shared__ unsigned short Bs[128 * 64];

    f4v acc[4][4];
    #pragma unroll
    for (int mt = 0; mt < 4; ++mt)
        #pragma unroll
        for (int nt = 0; nt < 4; ++nt) acc[mt][nt] = (f4v){0.f, 0.f, 0.f, 0.f};

    mfma_mainloop(Xb, Bt, As, Bs, m0, n0, t, acc);

    const float osc = (z == 0) ? QSCALE : 1.f;

    #pragma unroll
    for (int nt = 0; nt < 4; ++nt) {
        const int col = n0 + wn + nt * 16 + l15;   // 0..1023
        const int h = col >> 6, d = col & 63;
        const float bsc = bias[col];
        const int seg = d / 20;
        const int ds  = d - seg * 20;
        const float om   = __expf(-0.9210340372f * (float)(ds % 10));
        const float sign = (d & 1) ? 1.f : -1.f;

        #pragma unroll
        for (int mt = 0; mt < 4; ++mt) {
            const int mbase = m0 + wm + mt * 16 + qd * 4;
            const int b = mbase >> 11;
            const int sbase = mbase & 2047;
            if (z == 2) {
                ushort4 u;
                unsigned short* up = (unsigned short*)&u;
                #pragma unroll
                for (int r = 0; r < 4; ++r) up[r] = f2b_rne(acc[mt][nt][r] + bsc);
                *reinterpret_cast<ushort4*>(
                    Vt + ((size_t)(b * NH_ + h) * HD_ + d) * S_ + sbase) = u;
            } else {
                unsigned short* __restrict__ dst = (z == 0 ? Qb : Kb)
                    + ((size_t)(b * NH_ + h) * S_ + sbase) * HD_ + d;
                #pragma unroll
                for (int r = 0; r < 4; ++r) {
                    const int s = sbase + r;
                    float v = acc[mt][nt][r] + bsc;
                    const float xp = __shfl_xor(v, 1);
                    if (d < 60) {
                        const int rem = s & 255;
                        const float pos = (float)(seg == 0 ? (s >> 8)
                                               : (seg == 1 ? (rem >> 4) : (rem & 15)));
                        const float a = pos * om;
                        float sn, cs;
                        __sincosf(a, &sn, &cs);
                        v = v * cs + sign * xp * sn;
                    }
                    dst[(size_t)r * HD_] = f2b_rne(v * osc);
                }
            }
        }
    }
}

// ---------------------------------------------------------------------------
// Kernel: output projection GEMM + bias -> fp32 out. grid (8, 32).
// ---------------------------------------------------------------------------
__global__ __launch_bounds__(256) void gemm_out_kernel(
    const unsigned short* __restrict__ Cb, const unsigned short* __restrict__ Wot,
    const float* __restrict__ bo, float* __restrict__ out)
{
    const int n0 = blockIdx.x * 128, m0 = blockIdx.y * 128;
    const int t = threadIdx.x;
    const int w = t >> 6, lane = t & 63;
    const int l15 = lane & 15, qd = lane >> 4;
    const int wm = (w & 1) * 64, wn = (w >> 1) * 64;

    __shared__ unsigned short As[128 * 64];
    __shared__ unsigned short Bs[128 * 64];

    f4v acc[4][4];
    #pragma unroll
    for (int mt = 0; mt < 4; ++mt)
        #pragma unroll
        for (int nt = 0; nt < 4; ++nt) acc[mt][nt] = (f4v){0.f, 0.f, 0.f, 0.f};

    mfma_mainloop(Cb, Wot, As, Bs, m0, n0, t, acc);

    #pragma unroll
    for (int nt = 0; nt < 4; ++nt) {
        const int col = n0 + wn + nt * 16 + l15;
        const float bsc = bo[col];
        #pragma unroll
        for (int mt = 0; mt < 4; ++mt) {
            const int mbase = m0 + wm + mt * 16 + qd * 4;
            #pragma unroll
            for (int r = 0; r < 4; ++r)
                out[(size_t)(mbase + r) * HID_ + col] = acc[mt][nt][r] + bsc;
        }
    }
}

// ---------------------------------------------------------------------------
// Kernel: MFMA flash attention v3.
// Block = 4 waves, 128 q-rows (wave w owns q [w*32, w*32+32), two 16-row
// groups). Fixed-max softmax, exp2-folded (Q pre-scaled by QSCALE).
// Scores computed TRANSPOSED (Sᵀ = K·Qᵀ via operand swap) so the C-layout
// puts 4 consecutive kv per lane -> P written with ds_write_b64 after a
// 1-op v_perm truncation pack. l accumulated from the SAME truncated values
// (numerator/denominator consistent). K/V LDS frags reused across both
// q-groups. Grid 512 = exactly 2 blocks/CU (LDS 66 KB).
// ---------------------------------------------------------------------------
__global__ __launch_bounds__(256, 2) void attn_kernel(
    const bf16* __restrict__ Qb, const bf16* __restrict__ Kb,
    const bf16* __restrict__ Vt, unsigned short* __restrict__ CTX)
{
    const int q0 = blockIdx.x * 128;
    const int bh = blockIdx.y;
    const int b  = bh >> 4, h = bh & 15;
    const int t  = threadIdx.x;
    const int w  = t >> 6;
    const int lane = t & 63;
    const int l15 = lane & 15, qd = lane >> 4;

    __shared__ unsigned short Ks[128 * 64];    // [kv][d], chunk-swizzled by kv&7
    __shared__ unsigned short Vs[64 * 128];    // [d][kv], chunk-swizzled by d&15
    __shared__ unsigned short Ps[128 * 136];   // [q][kv], per-wave rows, pad 8

    // Q B-frags (pre-scaled by QSCALE in the projection epilogue)
    s8v bq[2][2];
    #pragma unroll
    for (int g = 0; g < 2; ++g) {
        const bf16* Qrow = Qb + ((size_t)bh * S_ + q0 + w * 32 + g * 16 + l15) * HD_ + qd * 8;
        bq[g][0] = *reinterpret_cast<const s8v*>(Qrow);
        bq[g][1] = *reinterpret_cast<const s8v*>(Qrow + 32);
    }

    f4v oacc[2][4];
    float lacc[2] = {0.f, 0.f};
    #pragma unroll
    for (int g = 0; g < 2; ++g)
        #pragma unroll
        for (int dt = 0; dt < 4; ++dt) oacc[g][dt] = (f4v){0.f, 0.f, 0.f, 0.f};

    const bf16* __restrict__ Kg = Kb + (size_t)bh * S_ * HD_;
    const bf16* __restrict__ Vg = Vt + (size_t)bh * HD_ * S_;

    const int krow = lane >> 3;                     // 0..7
    const int ksw  = ((lane & 7) ^ krow) * 8;       // K source chunk swizzle
    const int vrow = lane >> 4;                     // 0..3

    for (int k0 = 0; k0 < S_; k0 += 128) {
        __syncthreads();   // all waves done reading Ks/Vs from previous tile
        #pragma unroll
        for (int it = 0; it < 4; ++it) {
            gload_lds16(Kg + (size_t)(k0 + w * 32 + it * 8 + krow) * HD_ + ksw,
                        Ks + (w * 32 + it * 8) * 64);
        }
        #pragma unroll
        for (int it = 0; it < 4; ++it) {
            const int r = w * 16 + it * 4 + vrow;   // d row
            const int sv = ((lane & 15) ^ (r & 15)) * 8;
            gload_lds16(Vg + (size_t)r * S_ + k0 + sv,
                        Vs + (w * 16 + it * 4) * 128);
        }
        __syncthreads();

        // ---- scores (transposed): D[kv=nt*16+qd*4+r][q=w*32+g*16+l15]
        #pragma unroll
        for (int nt = 0; nt < 8; ++nt) {
            const unsigned short* kr = Ks + (nt * 16 + l15) * 64;
            const s8v ak0 = *reinterpret_cast<const s8v*>(kr + ((qd ^ (l15 & 7)) * 8));
            const s8v ak1 = *reinterpret_cast<const s8v*>(kr + (((qd + 4) ^ (l15 & 7)) * 8));
            #pragma unroll
            for (int g = 0; g < 2; ++g) {
                f4v zz = (f4v){0.f, 0.f, 0.f, 0.f};
                zz = __builtin_amdgcn_mfma_f32_16x16x32_bf16(ak0, bq[g][0], zz, 0, 0, 0);
                zz = __builtin_amdgcn_mfma_f32_16x16x32_bf16(ak1, bq[g][1], zz, 0, 0, 0);
                const float p0 = __builtin_amdgcn_exp2f(zz[0]);
                const float p1 = __builtin_amdgcn_exp2f(zz[1]);
                const float p2 = __builtin_amdgcn_exp2f(zz[2]);
                const float p3 = __builtin_amdgcn_exp2f(zz[3]);
                // truncation pack: u01 = {bf16(p1), bf16(p0)} in one v_perm
                const unsigned int u01 = __builtin_amdgcn_perm(
                    __float_as_uint(p1), __float_as_uint(p0), 0x07060302u);
                const unsigned int u23 = __builtin_amdgcn_perm(
                    __float_as_uint(p3), __float_as_uint(p2), 0x07060302u);
                // l from the SAME truncated values (consistency with PV)
                const float t0 = __uint_as_float(u01 << 16);
                const float t1 = __uint_as_float(u01 & 0xffff0000u);
                const float t2 = __uint_as_float(u23 << 16);
                const float t3 = __uint_as_float(u23 & 0xffff0000u);
                lacc[g] += (t0 + t1) + (t2 + t3);
                *reinterpret_cast<uint2*>(
                    Ps + (w * 32 + g * 16 + l15) * 136 + nt * 16 + qd * 4) =
                    make_uint2(u01, u23);
            }
        }
        // no barrier: wave w writes and reads only its own 32 P rows

        // ---- O += P @ V
        #pragma unroll
        for (int kc = 0; kc < 4; ++kc) {
            s8v ap[2];
            #pragma unroll
            for (int g = 0; g < 2; ++g)
                ap[g] = *reinterpret_cast<const s8v*>(
                    Ps + (w * 32 + g * 16 + l15) * 136 + kc * 32 + qd * 8);
            #pragma unroll
            for (int dt = 0; dt < 4; ++dt) {
                const s8v bv = *reinterpret_cast<const s8v*>(
                    Vs + (dt * 16 + l15) * 128 + (((kc * 4 + qd) ^ l15) & 15) * 8);
                oacc[0][dt] = __builtin_amdgcn_mfma_f32_16x16x32_bf16(ap[0], bv, oacc[0][dt], 0, 0, 0);
                oacc[1][dt] = __builtin_amdgcn_mfma_f32_16x16x32_bf16(ap[1], bv, oacc[1][dt], 0, 0, 0);
            }
        }
    }

    // ---- epilogue: reduce l across quads; O[q=qd*4+r][d=dt*16+l15] / l[q]
    #pragma unroll
    for (int g = 0; g < 2; ++g) {
        float ls = lacc[g];
        ls += __shfl_xor(ls, 16);
        ls += __shfl_xor(ls, 32);            // all lanes: l for q = w*32+g*16+l15
        #pragma unroll
        for (int r = 0; r < 4; ++r) {
            const float lr = __shfl(ls, qd * 4 + r);   // l for q-local = qd*4+r
            const float inv = 1.0f / lr;
            const int s = q0 + w * 32 + g * 16 + qd * 4 + r;
            unsigned short* __restrict__ dst =
                CTX + ((size_t)(b * S_ + s)) * HID_ + h * HD_ + l15;
            #pragma unroll
            for (int dt = 0; dt < 4; ++dt)
                dst[dt * 16] = f2b_rne(oacc[g][dt][r] * inv);
        }
    }
}

// ---------------------------------------------------------------------------
extern "C" void kernel_launch(void* const* d_in, const int* in_sizes, int n_in,
                              void* d_out, int out_size, void* d_ws, size_t ws_size,
                              hipStream_t stream)
{
    const float* X  = (const float*)d_in[0];
    const float* Wq = (const float*)d_in[1];
    const float* bq = (const float*)d_in[2];
    const float* Wk = (const float*)d_in[3];
    const float* bk = (const float*)d_in[4];
    const float* Wv = (const float*)d_in[5];
    const float* bv = (const float*)d_in[6];
    const float* Wo = (const float*)d_in[7];
    const float* bo = (const float*)d_in[8];
    float* out = (float*)d_out;

    // ws: Xb 4M | Wqt 1M | Wkt 1M | Wvt 1M | Wot 1M | Qb 4M | Kb 4M | Vt 4M | Cb 4M (bf16) = 48 MB
    const size_t QKV = (size_t)B_ * NH_ * S_ * HD_;   // 4,194,304
    unsigned short* Xb  = (unsigned short*)d_ws;
    unsigned short* Wqt = Xb  + QKV;
    unsigned short* Wkt = Wqt + (size_t)HID_ * HID_;
    unsigned short* Wvt = Wkt + (size_t)HID_ * HID_;
    unsigned short* Wot = Wvt + (size_t)HID_ * HID_;
    unsigned short* Qb  = Wot + (size_t)HID_ * HID_;
    unsigned short* Kb  = Qb + QKV;
    unsigned short* Vt  = Kb + QKV;
    unsigned short* Cb  = Vt + QKV;

    convert_x_kernel<<<4096, 256, 0, stream>>>(X, Xb);
    transpose_w_kernel<<<dim3(16, 16, 4), 256, 0, stream>>>(
        Wq, Wk, Wv, Wo, Wqt, Wkt, Wvt, Wot);
    gemm_qkv_kernel<<<dim3(8, 32, 3), 256, 0, stream>>>(
        Xb, Wqt, Wkt, Wvt, bq, bk, bv, Qb, Kb, Vt);
    attn_kernel<<<dim3(S_ / 128, B_ * NH_), 256, 0, stream>>>(
        (const bf16*)Qb, (const bf16*)Kb, (const bf16*)Vt, Cb);
    gemm_out_kernel<<<dim3(8, 32), 256, 0, stream>>>(Cb, Wot, bo, out);
}